// Round 9
// baseline (164.464 us; speedup 1.0000x reference)
//
#include <hip/hip_runtime.h>

// Trilinear interpolation of a 128^3 x 16 latent grid at 2M random points.
// 3-phase spatial counting sort:
//   A1: counting-sort points into 64 super-bins (segments in d_out, which is
//       fully overwritten by B afterwards).
//   A2: per super-bin, counting-sort its segment into 256 children -> 16384
//       fine bins (16x32x32; 8x4x4 grid cells each) in d_ws.
//   B : each block owns 4 consecutive bins, double-buffered LDS pipeline:
//       stage(next bin) via global_load_lds DMA + counted s_waitcnt vmcnt(7)
//       + raw s_barrier (never a full drain) while computing the current bin.
// Spill list + cleanup kernel guard the (>5 sigma) capacity overflow paths.

constexpr int   GRID_RES   = 128;
constexpr int   LATENT_DIM = 16;
constexpr float SCALE      = 126.0f;          // GRID_RES - 2

constexpr int NSUPER    = 64;                  // 4x4x4
constexpr int NCHILD    = 256;                 // 4x8x8 per super
constexpr int NFINE     = NSUPER * NCHILD;     // 16384 (16x32x32)
constexpr int CAP_F     = 192;                 // mean 128, sigma ~11.3
constexpr int SPILL_CAP = 16384;
constexpr int NROWS     = 9 * 5 * 5;           // 225 staged latent rows
constexpr int NB        = 4;                   // bins per block in phase B

// d_ws layout
constexpr size_t SCUR_OFF     = 0;             // 64 u32
constexpr size_t FCUR_OFF     = 1024;          // 16384 u32
constexpr size_t SPILLCUR_OFF = 66560;         // 1 u32
constexpr size_t CUR_BYTES    = 69632;         // memset region
constexpr size_t FINE_OFF     = CUR_BYTES;
constexpr size_t FINE_BYTES   = (size_t)NFINE * CAP_F * 16;
constexpr size_t SPILL_OFF    = FINE_OFF + FINE_BYTES;
constexpr size_t WS_NEEDED    = SPILL_OFF + (size_t)SPILL_CAP * 16;

typedef float fvec4 __attribute__((ext_vector_type(4)));
typedef const __attribute__((address_space(1))) unsigned int* gptr_t;
typedef __attribute__((address_space(3))) unsigned int*       lptr_t;

// ---- helpers ----------------------------------------------------------------

__device__ __forceinline__ void fine_bin(float x, float y, float z,
                                         int* s, int* c) {
    const int lx = min(max((int)floorf(x * SCALE), 0), 125);
    const int ly = min(max((int)floorf(y * SCALE), 0), 125);
    const int lz = min(max((int)floorf(z * SCALE), 0), 125);
    const int fbx = lx >> 3;   // [0,16)
    const int fby = ly >> 2;   // [0,32)
    const int fbz = lz >> 2;   // [0,32)
    *s = ((fbx >> 2) << 4) | ((fby >> 3) << 2) | (fbz >> 3);           // [0,64)
    *c = ((fbx & 3) << 6) | ((fby & 7) << 3) | (fbz & 7);              // [0,256)
}

__device__ __forceinline__ void corner_setup(
    float sx, float sy, float sz,
    int cx[2], int cy[2], int cz[2],
    float fx[2], float fy[2], float fz[2])
{
    const float bx = floorf(sx), by = floorf(sy), bz = floorf(sz);
    const int ix = (int)bx, iy = (int)by, iz = (int)bz;
    const float wbx = sx - bx, wby = sy - by, wbz = sz - bz;
    cx[0] = min(max(ix,     0), GRID_RES - 1);
    cx[1] = min(max(ix + 1, 0), GRID_RES - 1);
    cy[0] = min(max(iy,     0), GRID_RES - 1);
    cy[1] = min(max(iy + 1, 0), GRID_RES - 1);
    cz[0] = min(max(iz,     0), GRID_RES - 1);
    cz[1] = min(max(iz + 1, 0), GRID_RES - 1);
    fx[0] = 1.0f - wbx; fx[1] = wbx;
    fy[0] = 1.0f - wby; fy[1] = wby;
    fz[0] = 1.0f - wbz; fz[1] = wbz;
}

__device__ __forceinline__ fvec4 trilerp_q(
    const float* __restrict__ latents,
    const int cx[2], const int cy[2], const int cz[2],
    const float fx[2], const float fy[2], const float fz[2], int q)
{
    fvec4 acc = (fvec4)(0.0f);
    #pragma unroll
    for (int ox = 0; ox < 2; ++ox)
      #pragma unroll
      for (int oy = 0; oy < 2; ++oy)
        #pragma unroll
        for (int oz = 0; oz < 2; ++oz) {
            const int flat = cx[ox] * (GRID_RES * GRID_RES) + cy[oy] * GRID_RES + cz[oz];
            const float w = fx[ox] * fy[oy] * fz[oz];
            const fvec4 f = *reinterpret_cast<const fvec4*>(
                latents + (size_t)flat * LATENT_DIM + q * 4);
            acc += w * f;
        }
    return acc;
}

// ---- A1: counting-sort into 64 super-bins (segments in d_out) ---------------

__global__ __launch_bounds__(256) void binA1(
    const float* __restrict__ pts, int n_pts,
    unsigned* __restrict__ scur, fvec4* __restrict__ superSeg, int cap_s,
    unsigned* __restrict__ spillcur, fvec4* __restrict__ spillSeg)
{
    __shared__ unsigned cnt[NSUPER], base[NSUPER], off[NSUPER];
    const int t = threadIdx.x;
    if (t < NSUPER) { cnt[t] = 0; off[t] = 0; }
    __syncthreads();

    const int chunk = (n_pts + gridDim.x - 1) / gridDim.x;
    const int lo = blockIdx.x * chunk;
    const int hi = min(lo + chunk, n_pts);

    for (int p = lo + t; p < hi; p += 256) {
        int s, c;
        fine_bin(pts[3*p], pts[3*p+1], pts[3*p+2], &s, &c);
        atomicAdd(&cnt[s], 1u);
    }
    __syncthreads();
    if (t < NSUPER) base[t] = atomicAdd(&scur[t], cnt[t]);
    __syncthreads();
    for (int p = lo + t; p < hi; p += 256) {
        const float x = pts[3*p], y = pts[3*p+1], z = pts[3*p+2];
        int s, c;
        fine_bin(x, y, z, &s, &c);
        const unsigned slot = base[s] + atomicAdd(&off[s], 1u);
        fvec4 tp; tp.x = x; tp.y = y; tp.z = z; tp.w = __uint_as_float((unsigned)p);
        if (slot < (unsigned)cap_s) {
            superSeg[(size_t)s * cap_s + slot] = tp;
        } else {                                   // ~impossible; keep correct
            const unsigned sp = atomicAdd(spillcur, 1u);
            if (sp < (unsigned)SPILL_CAP) spillSeg[sp] = tp;
        }
    }
}

// ---- A2: refine each super-bin into its 256 children ------------------------

__global__ __launch_bounds__(256) void binA2(
    const fvec4* __restrict__ superSeg, int cap_s,
    const unsigned* __restrict__ scur,
    unsigned* __restrict__ fcur, fvec4* __restrict__ fineSeg,
    unsigned* __restrict__ spillcur, fvec4* __restrict__ spillSeg)
{
    constexpr int SLICES = 8;
    const int super = blockIdx.x / SLICES;
    const int slice = blockIdx.x % SLICES;
    const unsigned n = min(scur[super], (unsigned)cap_s);
    const unsigned lo = (unsigned)(((unsigned long long)n * slice) / SLICES);
    const unsigned hi = (unsigned)(((unsigned long long)n * (slice + 1)) / SLICES);

    __shared__ unsigned cnt[NCHILD], base[NCHILD], off[NCHILD];
    const int t = threadIdx.x;
    cnt[t] = 0; off[t] = 0;          // NCHILD == blockDim
    __syncthreads();

    for (unsigned i = lo + t; i < hi; i += 256) {
        const fvec4 tp = superSeg[(size_t)super * cap_s + i];
        int s, c;
        fine_bin(tp.x, tp.y, tp.z, &s, &c);
        atomicAdd(&cnt[c], 1u);
    }
    __syncthreads();
    base[t] = atomicAdd(&fcur[super * NCHILD + t], cnt[t]);
    __syncthreads();
    for (unsigned i = lo + t; i < hi; i += 256) {
        const fvec4 tp = superSeg[(size_t)super * cap_s + i];
        int s, c;
        fine_bin(tp.x, tp.y, tp.z, &s, &c);
        const unsigned slot = base[c] + atomicAdd(&off[c], 1u);
        if (slot < (unsigned)CAP_F) {
            fineSeg[(size_t)(super * NCHILD + c) * CAP_F + slot] = tp;
        } else {
            const unsigned sp = atomicAdd(spillcur, 1u);
            if (sp < (unsigned)SPILL_CAP) spillSeg[sp] = tp;
        }
    }
}

// ---- B: double-buffered per-bin pipeline ------------------------------------
// Bin covers cells [bx*8,+8) x [by*4,+4) x [bz*4,+4); staged tile 9x5x5 = 225
// rows (64 B each). LDS layout is quarter-major: 16-B unit u = q*225 + r
// (linear for global_load_lds DMA; bank windows start at 4*(q+r) mod 32).
// Per iteration: stage(next bin, other buf) + 3 unconditional tuple loads,
// then s_waitcnt vmcnt(7) (leaves exactly those 7 in flight) + raw s_barrier.

__global__ __launch_bounds__(256, 5) void binB(
    const fvec4* __restrict__ fineSeg, const unsigned* __restrict__ fcur,
    const float* __restrict__ latents, float* __restrict__ out)
{
    __shared__ __align__(16) float lat[2][4096];   // 2 x 16 KB (1024 units)

    const int blk  = blockIdx.x;                   // bins [blk*NB, blk*NB+NB)
    const int t    = threadIdx.x;
    const int wave = t >> 6, lane = t & 63;
    const int q    = t & 3,  lp   = t >> 2;

    // per-bin geometry
    int bxa[NB], bya[NB], bza[NB], ncnt[NB];
    const fvec4* sega[NB];
    #pragma unroll
    for (int j = 0; j < NB; ++j) {
        const int fid = blk * NB + j;
        const int super = fid >> 8, c = fid & 255;
        bxa[j] = ((super >> 4) << 2)       | (c >> 6);
        bya[j] = (((super >> 2) & 3) << 3) | ((c >> 3) & 7);
        bza[j] = ((super & 3) << 3)        | (c & 7);
        ncnt[j] = (int)min(fcur[fid], (unsigned)CAP_F);
        sega[j] = fineSeg + (size_t)fid * CAP_F;
    }

    // stage one bin's tile into buf: 4 global_load_lds_dwordx4 per wave
    auto stage = [&](int j, int buf) {
        const int bx = bxa[j], by = bya[j], bz = bza[j];
        #pragma unroll
        for (int k = 0; k < 4; ++k) {
            const int u  = wave * 64 + k * 256 + lane;   // 0..1023
            const int uc = min(u, NROWS * 4 - 1);        // clamp; pad units get dup data
            const int qq = uc / NROWS, r = uc - qq * NROWS;
            const int dx = r / 25, rem = r - dx * 25, dy = rem / 5, dz = rem - dy * 5;
            const int gx = min(bx * 8 + dx, 127);
            const int gy = min(by * 4 + dy, 127);
            const int gz = min(bz * 4 + dz, 127);
            const float* src = latents
                + ((size_t)(((gx << 7) | gy) << 7 | gz)) * LATENT_DIM + qq * 4;
            // wave-uniform LDS base (lane 0 of this chunk); HW adds lane*16
            float* dst = &lat[buf][(wave * 64 + k * 256) * 4];
            __builtin_amdgcn_global_load_lds((gptr_t)(const void*)src,
                                             (lptr_t)(void*)dst, 16, 0, 0);
        }
    };

    // unconditional (clamped-address) tuple loads: always 3 vmcnt entries
    auto tload = [&](int j, fvec4& t0, fvec4& t1, fvec4& t2) {
        const int hi = max(ncnt[j] - 1, 0);
        t0 = __builtin_nontemporal_load(&sega[j][min(lp,       hi)]);
        t1 = __builtin_nontemporal_load(&sega[j][min(lp +  64, hi)]);
        t2 = __builtin_nontemporal_load(&sega[j][min(lp + 128, hi)]);
    };

    // prologue: stage + tuples for bin 0
    stage(0, 0);
    fvec4 tc0, tc1, tc2;
    tload(0, tc0, tc1, tc2);

    #pragma unroll
    for (int i = 0; i < NB; ++i) {
        const int nxt = (i + 1 < NB) ? i + 1 : NB - 1;   // dummy re-stage on last
        stage(nxt, (i + 1) & 1);
        fvec4 tn0, tn1, tn2;
        tload(nxt, tn0, tn1, tn2);

        // wait for current bin's stage+tuples (7 newest = next bin's ops)
        asm volatile("s_waitcnt vmcnt(7)" ::: "memory");
        __builtin_amdgcn_s_barrier();
        __builtin_amdgcn_sched_barrier(0);

        const float* lbuf = lat[i & 1];
        const int bx = bxa[i], by = bya[i], bz = bza[i], n = ncnt[i];

        #pragma unroll
        for (int k = 0; k < 3; ++k) {
            if (lp + k * 64 < n) {
                const fvec4 tp = (k == 0) ? tc0 : (k == 1) ? tc1 : tc2;
                const unsigned idx = __float_as_uint(tp.w);
                const float sxv = tp.x * SCALE, syv = tp.y * SCALE, szv = tp.z * SCALE;
                const float bxf = floorf(sxv), byf = floorf(syv), bzf = floorf(szv);
                const int lx = (int)bxf - bx * 8;           // [0,7]
                const int ly = (int)byf - by * 4;           // [0,3]
                const int lz = (int)bzf - bz * 4;           // [0,3]
                const float wbx = sxv - bxf, wby = syv - byf, wbz = szv - bzf;
                const float fx[2] = {1.0f - wbx, wbx};
                const float fy[2] = {1.0f - wby, wby};
                const float fz[2] = {1.0f - wbz, wbz};

                fvec4 acc = (fvec4)(0.0f);
                #pragma unroll
                for (int ox = 0; ox < 2; ++ox)
                  #pragma unroll
                  for (int oy = 0; oy < 2; ++oy)
                    #pragma unroll
                    for (int oz = 0; oz < 2; ++oz) {
                        const int r = (lx + ox) * 25 + (ly + oy) * 5 + (lz + oz);
                        const fvec4 f = *reinterpret_cast<const fvec4*>(
                            &lbuf[(q * NROWS + r) * 4]);
                        acc += (fx[ox] * fy[oy] * fz[oz]) * f;
                    }

                __builtin_nontemporal_store(acc,
                    reinterpret_cast<fvec4*>(out + (size_t)idx * LATENT_DIM + q * 4));
            }
        }

        // all waves done reading buf[i&1] before it's restaged next iteration
        __builtin_amdgcn_s_barrier();

        tc0 = tn0; tc1 = tn1; tc2 = tn2;
    }
}

// ---- spill cleanup (normally n == 0) ----------------------------------------

__global__ __launch_bounds__(256) void spillK(
    const fvec4* __restrict__ spillSeg, const unsigned* __restrict__ spillcur,
    const float* __restrict__ latents, float* __restrict__ out)
{
    const unsigned n = min(*spillcur, (unsigned)SPILL_CAP);
    for (unsigned i = blockIdx.x * 256 + threadIdx.x; i < n; i += gridDim.x * 256) {
        const fvec4 tp = spillSeg[i];
        const unsigned idx = __float_as_uint(tp.w);
        int cx[2], cy[2], cz[2]; float fx[2], fy[2], fz[2];
        corner_setup(tp.x * SCALE, tp.y * SCALE, tp.z * SCALE, cx, cy, cz, fx, fy, fz);
        #pragma unroll
        for (int q = 0; q < 4; ++q) {
            const fvec4 acc = trilerp_q(latents, cx, cy, cz, fx, fy, fz, q);
            *reinterpret_cast<fvec4*>(out + (size_t)idx * LATENT_DIM + q * 4) = acc;
        }
    }
}

// ---- fallback: direct version ----------------------------------------------

__global__ __launch_bounds__(256) void trilerp_direct(
    const float* __restrict__ pts, const float* __restrict__ latents,
    float* __restrict__ out, int n_pts)
{
    const int tid = blockIdx.x * blockDim.x + threadIdx.x;
    const int p = tid >> 2;
    const int q = tid & 3;
    if (p >= n_pts) return;
    int cx[2], cy[2], cz[2]; float fx[2], fy[2], fz[2];
    corner_setup(pts[3*p] * SCALE, pts[3*p+1] * SCALE, pts[3*p+2] * SCALE,
                 cx, cy, cz, fx, fy, fz);
    const fvec4 acc = trilerp_q(latents, cx, cy, cz, fx, fy, fz, q);
    *reinterpret_cast<fvec4*>(out + (size_t)p * LATENT_DIM + q * 4) = acc;
}

// ---- launch -----------------------------------------------------------------

extern "C" void kernel_launch(void* const* d_in, const int* in_sizes, int n_in,
                              void* d_out, int out_size, void* d_ws, size_t ws_size,
                              hipStream_t stream) {
    const float* pts     = (const float*)d_in[0];
    const float* latents = (const float*)d_in[1];
    float* out = (float*)d_out;
    const int n_pts = in_sizes[0] / 3;

    const int cap_s = (int)(((size_t)out_size * 4) / (NSUPER * 16));  // tuples/super seg

    if (ws_size < WS_NEEDED || cap_s * (size_t)NSUPER * 16 > (size_t)out_size * 4 ||
        (size_t)cap_s < (size_t)n_pts / 16) {
        const int total = n_pts * 4;
        trilerp_direct<<<(total + 255) / 256, 256, 0, stream>>>(pts, latents, out, n_pts);
        return;
    }

    unsigned* scur     = (unsigned*)((char*)d_ws + SCUR_OFF);
    unsigned* fcur     = (unsigned*)((char*)d_ws + FCUR_OFF);
    unsigned* spillcur = (unsigned*)((char*)d_ws + SPILLCUR_OFF);
    fvec4*    fineSeg  = (fvec4*)((char*)d_ws + FINE_OFF);
    fvec4*    spillSeg = (fvec4*)((char*)d_ws + SPILL_OFF);
    fvec4*    superSeg = (fvec4*)d_out;                 // reused as scratch

    hipMemsetAsync(d_ws, 0, CUR_BYTES, stream);
    binA1<<<512, 256, 0, stream>>>(pts, n_pts, scur, superSeg, cap_s,
                                   spillcur, spillSeg);
    binA2<<<NSUPER * 8, 256, 0, stream>>>(superSeg, cap_s, scur,
                                          fcur, fineSeg, spillcur, spillSeg);
    binB<<<NFINE / NB, 256, 0, stream>>>(fineSeg, fcur, latents, out);
    spillK<<<16, 256, 0, stream>>>(spillSeg, spillcur, latents, out);
}